// Round 5
// baseline (328.600 us; speedup 1.0000x reference)
//
#include <hip/hip_runtime.h>

// YOLO loss, forward only. pred/target: (16384, 7, 7, 30) fp32, out: scalar fp32.
// S=7, B=2, CLS=20, N=30, LAMBDA_COORD=5, LAMBDA_NOOBJ=0.5, BATCH=16384.
// NOTE: reference conf_loc = arange(B)*B+4 = [4,6] (not [4,9]) — mirrored here.
//
// R5: single coalesced sweep + LDS scatter of box fields, LDS-only phase 2.
//   R1: 120 B-stride per-thread loads -> ~1800 L1 tag lookups/wave -> 75 us.
//   R2: LDS ds_add atomics (13-way same-addr serialization) -> 104 us; BUT its
//       plain scatter stores were cheap (3.9k conflicts total).
//   R3/R4: gated coalesced sweep good, but pass-2 GLOBAL re-gathers caused
//       FETCH 203 MB + WRITE 107 MB and latency serialization -> 116 us.
//   R5: sweep accumulates class+noobj in registers (gate via 2 KB t4s table),
//       scatters p[0..9]/t[0..3] to padded LDS (plain stores, no atomics),
//       phase 2 does IoU from LDS only. No global traffic beyond the stream.

#define TPB 256
#define NPER 30
#define CPB 512                     // cells per block
#define TILE_FLOATS (CPB * NPER)    // 15360 floats per array per tile
#define R_TOTAL (16384 * 7 * 7)     // 802816 cells
#define NBLOCKS (R_TOTAL / CPB)     // 1568
#define PB_STRIDE 11                // p[0..9] + pad (odd stride: <=2-way, free)
#define TB_STRIDE 5                 // t[0..3] + slot 4 unused (odd stride)

__global__ __launch_bounds__(TPB, 4) void yolo_loss_kernel(
    const float* __restrict__ pred, const float* __restrict__ target,
    float* __restrict__ out)
{
    __shared__ float pb[CPB * PB_STRIDE];   // 22528 B
    __shared__ float tb[CPB * TB_STRIDE];   // 10240 B
    __shared__ float t4s[CPB];              //  2048 B
    __shared__ float red[TPB / 64];

    const int tid = threadIdx.x;
    const size_t tbase = (size_t)blockIdx.x * TILE_FLOATS;
    const float* gp = pred + tbase;
    const float* gt = target + tbase;

    // ---- Pre-pass: gather the 512 gates (also warms L2 for the sweep) ----
    t4s[tid]       = gt[(size_t)tid * NPER + 4];
    t4s[tid + TPB] = gt[(size_t)(tid + TPB) * NPER + 4];
    __syncthreads();

    float acc_cls = 0.0f;   // sum over class slots, gated by (t4 == 1)
    float acc_no  = 0.0f;   // sum over conf_loc [4,6], gated by (t4 == 0)

    // ---- Sweep: fully-coalesced float4, register accumulation + LDS scatter ----
    const float4* gp4 = (const float4*)gp;
    const float4* gt4 = (const float4*)gt;
    #pragma unroll
    for (int k = 0; k < TILE_FLOATS / (4 * TPB); k++) {   // 15 iterations
        int F = tid + k * TPB;
        float4 vp = gp4[F];
        float4 vt = gt4[F];
        unsigned f0 = 4u * (unsigned)F;            // first float index (even)
        unsigned c0 = (f0 * 34953u) >> 20;         // f0 / 30 (exact, f0 < 74898)
        int s0 = (int)(f0 - c0 * 30u);             // f0 % 30, even, 0..28
        float gA = t4s[c0];
        float gB = (s0 == 28) ? t4s[c0 + 1] : gA;  // wrap only when s0 == 28

        float pe[4] = {vp.x, vp.y, vp.z, vp.w};
        float te[4] = {vt.x, vt.y, vt.z, vt.w};
        #pragma unroll
        for (int i = 0; i < 4; i++) {
            int s = s0 + i;
            unsigned c = c0;
            float g = gA;
            if (s >= 30) { s -= 30; c = c0 + 1; g = gB; }
            float d = pe[i] - te[i];
            float q = d * d;
            acc_cls += ((s >= 10) && (g == 1.0f)) ? q : 0.0f;
            acc_no  += (((s == 4) | (s == 6)) && (g == 0.0f)) ? q : 0.0f;
            // scatter box fields (plain stores, no atomics)
            if (s < 10) pb[c * PB_STRIDE + s] = pe[i];
            if (s < 4)  tb[c * TB_STRIDE + s] = te[i];
        }
    }
    __syncthreads();

    // ---- Phase 2: obj cells only, all operands from LDS ----
    float acc_obj = 0.0f;
    #pragma unroll
    for (int cc = 0; cc < CPB / TPB; cc++) {
        int c = tid + cc * TPB;
        if (t4s[c] == 1.0f) {
            const float* p = &pb[c * PB_STRIDE];
            const float* t = &tb[c * TB_STRIDE];

            // target box -> xyxy (mirror reference float op order)
            float tx1 = t[0] - t[2] * 0.5f, ty1 = t[1] - t[3] * 0.5f;
            float tx2 = t[0] + t[2] * 0.5f, ty2 = t[1] + t[3] * 0.5f;
            float area2 = (tx2 - tx1) * (ty2 - ty1);

            // box 0: p[0..4]
            float ax1 = p[0] - p[2] * 0.5f, ay1 = p[1] - p[3] * 0.5f;
            float ax2 = p[0] + p[2] * 0.5f, ay2 = p[1] + p[3] * 0.5f;
            float w0 = fmaxf(fminf(ax2, tx2) - fmaxf(ax1, tx1), 0.0f);
            float h0 = fmaxf(fminf(ay2, ty2) - fmaxf(ay1, ty1), 0.0f);
            float inter0 = w0 * h0;
            float uni0 = (ax2 - ax1) * (ay2 - ay1) + area2 - inter0;
            float iou0 = (uni0 > 0.0f) ? (inter0 / uni0) : 0.0f;

            // box 1: p[5..9]
            float bx1 = p[5] - p[7] * 0.5f, by1 = p[6] - p[8] * 0.5f;
            float bx2 = p[5] + p[7] * 0.5f, by2 = p[6] + p[8] * 0.5f;
            float w1 = fmaxf(fminf(bx2, tx2) - fmaxf(bx1, tx1), 0.0f);
            float h1 = fmaxf(fminf(by2, ty2) - fmaxf(by1, ty1), 0.0f);
            float inter1 = w1 * h1;
            float uni1 = (bx2 - bx1) * (by2 - by1) + area2 - inter1;
            float iou1 = (uni1 > 0.0f) ? (inter1 / uni1) : 0.0f;

            // argmax over 2 -> first max index on ties
            bool j1 = (iou1 > iou0);
            float max_iou = fmaxf(iou0, iou1);
            float r0 = j1 ? p[5] : p[0];
            float r1 = j1 ? p[6] : p[1];
            float r2 = j1 ? p[7] : p[2];
            float r3 = j1 ? p[8] : p[3];
            float r4 = j1 ? p[9] : p[4];

            float dx = r0 - t[0];
            float dy = r1 - t[1];
            float sw = sqrtf(fmaxf(r2, 0.0f)) - sqrtf(fmaxf(t[2], 0.0f));
            float sh = sqrtf(fmaxf(r3, 0.0f)) - sqrtf(fmaxf(t[3], 0.0f));
            float coord = dx * dx + dy * dy + sw * sw + sh * sh;
            float dc = r4 - max_iou;
            acc_obj += 5.0f * coord + dc * dc;
        }
    }

    float sum = acc_cls + 0.5f * acc_no + acc_obj;

    // wave-64 reduction -> per-block atomic
    #pragma unroll
    for (int off = 32; off > 0; off >>= 1)
        sum += __shfl_down(sum, off, 64);
    if ((tid & 63) == 0) red[tid >> 6] = sum;
    __syncthreads();
    if (tid == 0) {
        float s = red[0] + red[1] + red[2] + red[3];
        atomicAdd(out, s * (1.0f / 16384.0f));
    }
}

extern "C" void kernel_launch(void* const* d_in, const int* in_sizes, int n_in,
                              void* d_out, int out_size, void* d_ws, size_t ws_size,
                              hipStream_t stream) {
    const float* pred = (const float*)d_in[0];
    const float* target = (const float*)d_in[1];
    float* out = (float*)d_out;
    // d_out is poisoned with 0xAA before every launch; we accumulate into it.
    hipMemsetAsync(out, 0, sizeof(float), stream);
    yolo_loss_kernel<<<NBLOCKS, TPB, 0, stream>>>(pred, target, out);
}

// Round 6
// 218.142 us; speedup vs baseline: 1.5064x; 1.5064x over previous
//
#include <hip/hip_runtime.h>

// YOLO loss, forward only. pred/target: (16384, 7, 7, 30) fp32, out: scalar fp32.
// S=7, B=2, CLS=20, N=30, LAMBDA_COORD=5, LAMBDA_NOOBJ=0.5, BATCH=16384.
// NOTE: reference conf_loc = arange(B)*B+4 = [4,6] (not [4,9]) — mirrored here.
//
// R6 = R5 with the scratch spill eliminated.
//   R4/R5 post-mortem: VGPR_Count=64 + WRITE_SIZE 107/182 MB => the fully
//   unrolled 15-iter float4 sweep hoisted ~30 float4 loads (~120 live VGPRs),
//   blew the launch_bounds(256,4) cap of 128, and spilled to scratch (global
//   memory). The spill traffic, not the sweep structure, was the regression.
//   Fix: #pragma unroll 1 on the sweep (<=2 float4 in flight; wave-level MLP
//   suffices) + launch_bounds(256,2) (VGPR cap 256). Everything else is the
//   R5 structure, which passed correctness:
//     - coalesced float4 sweep, class+noobj accumulated in registers gated by
//       a 2 KB LDS t4 table (no atomics),
//     - box fields p[0..9]/t[0..3] scattered to padded LDS via plain stores,
//     - obj-cell IoU phase entirely from LDS (no global re-fetch).

#define TPB 256
#define NPER 30
#define CPB 512                     // cells per block
#define TILE_FLOATS (CPB * NPER)    // 15360 floats per array per tile
#define R_TOTAL (16384 * 7 * 7)     // 802816 cells
#define NBLOCKS (R_TOTAL / CPB)     // 1568
#define PB_STRIDE 11                // p[0..9] + pad (odd stride: <=2-way, free)
#define TB_STRIDE 5                 // t[0..3] + pad (odd stride)

__global__ __launch_bounds__(TPB, 2) void yolo_loss_kernel(
    const float* __restrict__ pred, const float* __restrict__ target,
    float* __restrict__ out)
{
    __shared__ float pb[CPB * PB_STRIDE];   // 22528 B
    __shared__ float tb[CPB * TB_STRIDE];   // 10240 B
    __shared__ float t4s[CPB];              //  2048 B
    __shared__ float red[TPB / 64];

    const int tid = threadIdx.x;
    const size_t tbase = (size_t)blockIdx.x * TILE_FLOATS;
    const float* gp = pred + tbase;
    const float* gt = target + tbase;

    // ---- Pre-pass: gather the 512 gates ----
    t4s[tid]       = gt[(size_t)tid * NPER + 4];
    t4s[tid + TPB] = gt[(size_t)(tid + TPB) * NPER + 4];
    __syncthreads();

    float acc_cls = 0.0f;   // sum over class slots, gated by (t4 == 1)
    float acc_no  = 0.0f;   // sum over conf_loc [4,6], gated by (t4 == 0)

    // ---- Sweep: coalesced float4, register accumulation + LDS scatter ----
    // unroll 1: keep <=2 float4 loads in flight per thread so the register
    // allocator never spills (R4/R5 lesson). Wave-level parallelism (16
    // waves/CU) provides the MLP.
    const float4* gp4 = (const float4*)gp;
    const float4* gt4 = (const float4*)gt;
    #pragma unroll 1
    for (int k = 0; k < TILE_FLOATS / (4 * TPB); k++) {   // 15 iterations
        int F = tid + k * TPB;
        float4 vp = gp4[F];
        float4 vt = gt4[F];
        unsigned f0 = 4u * (unsigned)F;            // first float index (even)
        unsigned c0 = (f0 * 34953u) >> 20;         // f0 / 30 (exact, f0 < 74898)
        int s0 = (int)(f0 - c0 * 30u);             // f0 % 30, even, 0..28
        float gA = t4s[c0];
        float gB = (s0 == 28) ? t4s[c0 + 1] : gA;  // wrap only when s0 == 28

        float pe[4] = {vp.x, vp.y, vp.z, vp.w};
        float te[4] = {vt.x, vt.y, vt.z, vt.w};
        #pragma unroll
        for (int i = 0; i < 4; i++) {
            int s = s0 + i;
            unsigned c = c0;
            float g = gA;
            if (s >= 30) { s -= 30; c = c0 + 1; g = gB; }
            float d = pe[i] - te[i];
            float q = d * d;
            acc_cls += ((s >= 10) && (g == 1.0f)) ? q : 0.0f;
            acc_no  += (((s == 4) | (s == 6)) && (g == 0.0f)) ? q : 0.0f;
            // scatter box fields (plain stores, no atomics)
            if (s < 10) pb[c * PB_STRIDE + s] = pe[i];
            if (s < 4)  tb[c * TB_STRIDE + s] = te[i];
        }
    }
    __syncthreads();

    // ---- Phase 2: obj cells only, all operands from LDS ----
    float acc_obj = 0.0f;
    #pragma unroll 1
    for (int cc = 0; cc < CPB / TPB; cc++) {
        int c = tid + cc * TPB;
        if (t4s[c] == 1.0f) {
            const float* p = &pb[c * PB_STRIDE];
            const float* t = &tb[c * TB_STRIDE];

            // target box -> xyxy (mirror reference float op order)
            float tx1 = t[0] - t[2] * 0.5f, ty1 = t[1] - t[3] * 0.5f;
            float tx2 = t[0] + t[2] * 0.5f, ty2 = t[1] + t[3] * 0.5f;
            float area2 = (tx2 - tx1) * (ty2 - ty1);

            // box 0: p[0..4]
            float ax1 = p[0] - p[2] * 0.5f, ay1 = p[1] - p[3] * 0.5f;
            float ax2 = p[0] + p[2] * 0.5f, ay2 = p[1] + p[3] * 0.5f;
            float w0 = fmaxf(fminf(ax2, tx2) - fmaxf(ax1, tx1), 0.0f);
            float h0 = fmaxf(fminf(ay2, ty2) - fmaxf(ay1, ty1), 0.0f);
            float inter0 = w0 * h0;
            float uni0 = (ax2 - ax1) * (ay2 - ay1) + area2 - inter0;
            float iou0 = (uni0 > 0.0f) ? (inter0 / uni0) : 0.0f;

            // box 1: p[5..9]
            float bx1 = p[5] - p[7] * 0.5f, by1 = p[6] - p[8] * 0.5f;
            float bx2 = p[5] + p[7] * 0.5f, by2 = p[6] + p[8] * 0.5f;
            float w1 = fmaxf(fminf(bx2, tx2) - fmaxf(bx1, tx1), 0.0f);
            float h1 = fmaxf(fminf(by2, ty2) - fmaxf(by1, ty1), 0.0f);
            float inter1 = w1 * h1;
            float uni1 = (bx2 - bx1) * (by2 - by1) + area2 - inter1;
            float iou1 = (uni1 > 0.0f) ? (inter1 / uni1) : 0.0f;

            // argmax over 2 -> first max index on ties
            bool j1 = (iou1 > iou0);
            float max_iou = fmaxf(iou0, iou1);
            float r0 = j1 ? p[5] : p[0];
            float r1 = j1 ? p[6] : p[1];
            float r2 = j1 ? p[7] : p[2];
            float r3 = j1 ? p[8] : p[3];
            float r4 = j1 ? p[9] : p[4];

            float dx = r0 - t[0];
            float dy = r1 - t[1];
            float sw = sqrtf(fmaxf(r2, 0.0f)) - sqrtf(fmaxf(t[2], 0.0f));
            float sh = sqrtf(fmaxf(r3, 0.0f)) - sqrtf(fmaxf(t[3], 0.0f));
            float coord = dx * dx + dy * dy + sw * sw + sh * sh;
            float dc = r4 - max_iou;
            acc_obj += 5.0f * coord + dc * dc;
        }
    }

    float sum = acc_cls + 0.5f * acc_no + acc_obj;

    // wave-64 reduction -> per-block atomic
    #pragma unroll
    for (int off = 32; off > 0; off >>= 1)
        sum += __shfl_down(sum, off, 64);
    if ((tid & 63) == 0) red[tid >> 6] = sum;
    __syncthreads();
    if (tid == 0) {
        float s = red[0] + red[1] + red[2] + red[3];
        atomicAdd(out, s * (1.0f / 16384.0f));
    }
}

extern "C" void kernel_launch(void* const* d_in, const int* in_sizes, int n_in,
                              void* d_out, int out_size, void* d_ws, size_t ws_size,
                              hipStream_t stream) {
    const float* pred = (const float*)d_in[0];
    const float* target = (const float*)d_in[1];
    float* out = (float*)d_out;
    // d_out is poisoned with 0xAA before every launch; we accumulate into it.
    hipMemsetAsync(out, 0, sizeof(float), stream);
    yolo_loss_kernel<<<NBLOCKS, TPB, 0, stream>>>(pred, target, out);
}